// Round 1
// baseline (395.044 us; speedup 1.0000x reference)
//
#include <hip/hip_runtime.h>
#include <hip/hip_bf16.h>

typedef __bf16 bf16x8 __attribute__((ext_vector_type(8)));
typedef float floatx4 __attribute__((ext_vector_type(4)));

#define ROWK 200   // zt row stride in bf16 elements (192 + 8 pad)
#define ZROWS 112  // 100 used rows (4 pixels * 25 w), padded to 7 n-tiles * 16

// ---------------- prep: build Wp (bf16, A-operand order), effAT, bias2 ----------------
__global__ void sgc_prep(const float* __restrict__ W, const float* __restrict__ b,
                         const float* __restrict__ A, const float* __restrict__ edge,
                         const float* __restrict__ adA,
                         __hip_bfloat16* __restrict__ Wp, float* __restrict__ effAT,
                         float* __restrict__ bias2) {
  int tid = blockIdx.x * blockDim.x + threadIdx.x;
  int nthr = gridDim.x * blockDim.x;
  // Wp[c*192 + k*64 + ci] = bf16(W[(k*128+c)*64 + ci])   (24576 elems)
  for (int i = tid; i < 24576; i += nthr) {
    int c = i / 192; int r = i - c * 192; int k = r >> 6; int ci = r & 63;
    Wp[i] = __float2bfloat16(W[(k * 128 + c) * 64 + ci]);
  }
  // effAT[(k*25+w)*28 + v] = A[k][v][w]*edge + adA   (cols padded 25->28 with 0)
  for (int i = tid; i < 2100; i += nthr) {
    int kw = i / 28; int v = i - kw * 28;
    int k = kw / 25; int w = kw - k * 25;
    float val = 0.f;
    if (v < 25) {
      int idx = (k * 25 + v) * 25 + w;
      val = A[idx] * edge[idx] + adA[idx];
    }
    effAT[i] = val;
  }
  // bias2[c*25+w] = sum_k b[k*128+c] * sum_v effA[k][v][w]   (3200 elems)
  for (int i = tid; i < 3200; i += nthr) {
    int c = i / 25; int w = i - c * 25;
    float s = 0.f;
    for (int k = 0; k < 3; k++) {
      float sv = 0.f;
      for (int v = 0; v < 25; v++) {
        int idx = (k * 25 + v) * 25 + w;
        sv += A[idx] * edge[idx] + adA[idx];
      }
      s += b[k * 128 + c] * sv;
    }
    bias2[i] = s;
  }
}

// ---------------- main fused kernel: 4 pixels per block ----------------
__global__ __launch_bounds__(256, 2)
void sgc_main(const float* __restrict__ x,
              const __hip_bfloat16* __restrict__ Wp,
              const float* __restrict__ effAT,
              const float* __restrict__ bias2,
              float* __restrict__ out) {
  __shared__ __hip_bfloat16 zt[ZROWS * ROWK];
  const int tid = threadIdx.x;
  const int lane = tid & 63;
  const int wv = tid >> 6;   // wave id; also the pixel this wave stages
  const int blk = blockIdx.x;

  const int col = lane & 15;
  const int quad = lane >> 4;
  const int kb = quad * 8;

  // ---- preload W' A-fragments: wave wv owns m-tiles {2wv, 2wv+1} (c in [32wv,32wv+32)) ----
  bf16x8 afr[2][6];
#pragma unroll
  for (int mtl = 0; mtl < 2; mtl++) {
    int c = (2 * wv + mtl) * 16 + col;
    const __hip_bfloat16* wrow = Wp + c * 192;
#pragma unroll
    for (int ks = 0; ks < 6; ks++)
      afr[mtl][ks] = *(const bf16x8*)(wrow + ks * 32 + kb);
  }

  // ---- init accumulators with bias2 (folds the bias add; garbage cols nn>=100 harmless) ----
  floatx4 acc[2][7];
#pragma unroll
  for (int nt = 0; nt < 7; nt++) {
    int nn = nt * 16 + col;
    int p = (nn * 41) >> 10;       // floor(nn/25), exact for nn < 112
    int w = nn - p * 25;
#pragma unroll
    for (int mtl = 0; mtl < 2; mtl++) {
      int c0 = (2 * wv + mtl) * 16 + quad * 4;
#pragma unroll
      for (int r = 0; r < 4; r++)
        acc[mtl][nt][r] = bias2[(c0 + r) * 25 + w];
    }
  }

  // ---- stage A: z-row for pixel p=wv, channel ci=lane -> LDS (B-operand layout) ----
  {
    const int p = wv, ci = lane;
    const int g = blk * 4 + p;
    const int n = g >> 8, t = g & 255;
    const float* xrow = x + ((size_t)(n * 64 + ci) * 256 + t) * 25;
    float xr[25];
#pragma unroll
    for (int v = 0; v < 25; v++) xr[v] = xrow[v];
    for (int kw = 0; kw < 75; kw++) {
      const float* colp = effAT + kw * 28;
      float a = 0.f;
#pragma unroll
      for (int v = 0; v < 25; v++) a = fmaf(xr[v], colp[v], a);
      int k = (kw < 25) ? 0 : ((kw < 50) ? 1 : 2);
      int w = kw - k * 25;
      zt[(p * 25 + w) * ROWK + k * 64 + ci] = __float2bfloat16(a);
    }
  }
  __syncthreads();

  // ---- stage B: out[c][(p,w)] = W' @ z  (M=128 as 8 m-tiles over 4 waves, N=112, K=192) ----
  const __hip_bfloat16* ztp = zt;
#pragma unroll
  for (int ks = 0; ks < 6; ks++) {
    bf16x8 bfr[7];
#pragma unroll
    for (int nt = 0; nt < 7; nt++)
      bfr[nt] = *(const bf16x8*)(ztp + (nt * 16 + col) * ROWK + ks * 32 + kb);
#pragma unroll
    for (int nt = 0; nt < 7; nt++) {
      acc[0][nt] = __builtin_amdgcn_mfma_f32_16x16x32_bf16(afr[0][ks], bfr[nt], acc[0][nt], 0, 0, 0);
      acc[1][nt] = __builtin_amdgcn_mfma_f32_16x16x32_bf16(afr[1][ks], bfr[nt], acc[1][nt], 0, 0, 0);
    }
  }

  // ---- epilogue: C/D layout col=lane&15 (nn), row=quad*4+reg (c) ----
#pragma unroll
  for (int nt = 0; nt < 7; nt++) {
    int nn = nt * 16 + col;
    if (nn >= 100) continue;
    int p = (nn * 41) >> 10;
    int w = nn - p * 25;
    int g = blk * 4 + p;
    int n = g >> 8, t = g & 255;
#pragma unroll
    for (int mtl = 0; mtl < 2; mtl++) {
      int c0 = (2 * wv + mtl) * 16 + quad * 4;
      size_t base = ((size_t)(n * 128 + c0) * 256 + t) * 25 + w;
#pragma unroll
      for (int r = 0; r < 4; r++)
        out[base + (size_t)r * 6400] = acc[mtl][nt][r];
    }
  }
}

extern "C" void kernel_launch(void* const* d_in, const int* in_sizes, int n_in,
                              void* d_out, int out_size, void* d_ws, size_t ws_size,
                              hipStream_t stream) {
  const float* x    = (const float*)d_in[0];
  const float* W    = (const float*)d_in[1];
  const float* b    = (const float*)d_in[2];
  const float* A    = (const float*)d_in[3];
  const float* edge = (const float*)d_in[4];
  const float* adA  = (const float*)d_in[5];
  float* out = (float*)d_out;

  char* ws = (char*)d_ws;
  __hip_bfloat16* Wp = (__hip_bfloat16*)ws;        // 49152 B
  float* effAT = (float*)(ws + 49152);             // 8400 B
  float* bias2 = (float*)(ws + 57600);             // 12800 B

  sgc_prep<<<64, 256, 0, stream>>>(W, b, A, edge, adA, Wp, effAT, bias2);
  sgc_main<<<4096, 256, 0, stream>>>(x, Wp, effAT, bias2, out);
}

// Round 2
// 380.535 us; speedup vs baseline: 1.0381x; 1.0381x over previous
//
#include <hip/hip_runtime.h>
#include <hip/hip_bf16.h>

typedef __bf16 bf16x8 __attribute__((ext_vector_type(8)));
typedef __bf16 bf16x4 __attribute__((ext_vector_type(4)));
typedef float floatx4 __attribute__((ext_vector_type(4)));
typedef float floatx4u __attribute__((ext_vector_type(4), aligned(4)));

#define ROWK 200   // zt row stride in bf16 elements (192 + 8 pad)
#define ZROWS 112  // 100 used rows (4 pixels * 25 w), padded to 7 n-tiles * 16

// ---------------- prep: build Wp (bf16, A-operand order), effAB (bf16 B-operand), bias2 ----------------
__global__ void sgc_prep(const float* __restrict__ W, const float* __restrict__ b,
                         const float* __restrict__ A, const float* __restrict__ edge,
                         const float* __restrict__ adA,
                         __hip_bfloat16* __restrict__ Wp, __hip_bfloat16* __restrict__ effAB,
                         float* __restrict__ bias2) {
  int tid = blockIdx.x * blockDim.x + threadIdx.x;
  int nthr = gridDim.x * blockDim.x;
  // Wp[c*192 + k*64 + ci] = bf16(W[(k*128+c)*64 + ci])   (24576 elems)
  for (int i = tid; i < 24576; i += nthr) {
    int c = i / 192; int r = i - c * 192; int k = r >> 6; int ci = r & 63;
    Wp[i] = __float2bfloat16(W[(k * 128 + c) * 64 + ci]);
  }
  // effAB[n*32 + v] = bf16(effA[k=n/25][v][w=n%25]), n<75 && v<25, else 0  (2560 elems)
  for (int i = tid; i < 2560; i += nthr) {
    int n = i >> 5; int v = i & 31;
    float val = 0.f;
    if (n < 75 && v < 25) {
      int k = n / 25; int w = n - k * 25;
      int idx = (k * 25 + v) * 25 + w;
      val = A[idx] * edge[idx] + adA[idx];
    }
    effAB[i] = __float2bfloat16(val);
  }
  // bias2[c*25+w] = sum_k b[k*128+c] * sum_v effA[k][v][w]   (3200 elems, fp32 exact)
  for (int i = tid; i < 3200; i += nthr) {
    int c = i / 25; int w = i - c * 25;
    float s = 0.f;
    for (int k = 0; k < 3; k++) {
      float sv = 0.f;
      for (int v = 0; v < 25; v++) {
        int idx = (k * 25 + v) * 25 + w;
        sv += A[idx] * edge[idx] + adA[idx];
      }
      s += b[k * 128 + c] * sv;
    }
    bias2[i] = s;
  }
}

// ---------------- main fused kernel: 4 pixels per block, both stages MFMA ----------------
__global__ __launch_bounds__(256, 3)
void sgc_main(const float* __restrict__ x,
              const __hip_bfloat16* __restrict__ Wp,
              const __hip_bfloat16* __restrict__ effAB,
              const float* __restrict__ bias2,
              float* __restrict__ out) {
  __shared__ __hip_bfloat16 zt[ZROWS * ROWK];
  const int tid = threadIdx.x;
  const int lane = tid & 63;
  const int wv = tid >> 6;   // wave id == the pixel this wave computes in stage A
  const int blk = blockIdx.x;

  const int col = lane & 15;
  const int quad = lane >> 4;
  const int kb = quad * 8;

  // ---- effA B-fragments: 5 n-tiles covering n=(k*25+w) in [0,80) ----
  bf16x8 bA[5];
#pragma unroll
  for (int nt = 0; nt < 5; nt++)
    bA[nt] = *(const bf16x8*)(effAB + (nt * 16 + col) * 32 + kb);

  // ---- stage A (MFMA): pixel p=wv; z[ci][(k,w)] = x[ci][v] @ effA[v][(k,w)] ----
  {
    const int g = blk * 4 + wv;
    const int n0 = g >> 8, t = g & 255;
    const float* xbase = x + (size_t)(n0 * 64) * 6400 + (size_t)t * 25;
#pragma unroll
    for (int mt = 0; mt < 4; mt++) {
      const int ci = mt * 16 + col;
      const float* xr = xbase + (size_t)ci * 6400;
      // A-frag: m=ci(col), k=v=kb+j ; v>=25 zero-padded
      bf16x8 xa;
      if (quad < 3) {
        floatx4u a = *(const floatx4u*)(xr + kb);
        floatx4u c = *(const floatx4u*)(xr + kb + 4);
        xa = (bf16x8){(__bf16)a.x, (__bf16)a.y, (__bf16)a.z, (__bf16)a.w,
                      (__bf16)c.x, (__bf16)c.y, (__bf16)c.z, (__bf16)c.w};
      } else {
        float v24 = xr[24];  // kb==24: only v=24 valid
        xa = (bf16x8){(__bf16)v24, (__bf16)0.f, (__bf16)0.f, (__bf16)0.f,
                      (__bf16)0.f, (__bf16)0.f, (__bf16)0.f, (__bf16)0.f};
      }
      floatx4 zacc[5];
#pragma unroll
      for (int nt = 0; nt < 5; nt++) {
        zacc[nt] = (floatx4){0.f, 0.f, 0.f, 0.f};
        zacc[nt] = __builtin_amdgcn_mfma_f32_16x16x32_bf16(xa, bA[nt], zacc[nt], 0, 0, 0);
      }
      // write z -> LDS in stage-B B-operand layout: zt[(p*25+w)*ROWK + k*64 + ci]
      // C/D: col(n)=lane&15 -> n=nt*16+col ; row(ci)=mt*16+quad*4+r
#pragma unroll
      for (int nt = 0; nt < 5; nt++) {
        int nn = nt * 16 + col;
        if (nn < 75) {
          int k = (nn * 41) >> 10;     // floor(nn/25)
          int w = nn - k * 25;
          bf16x4 zb = (bf16x4){(__bf16)zacc[nt][0], (__bf16)zacc[nt][1],
                               (__bf16)zacc[nt][2], (__bf16)zacc[nt][3]};
          *(bf16x4*)(zt + (wv * 25 + w) * ROWK + k * 64 + mt * 16 + quad * 4) = zb;
        }
      }
    }
  }

  // ---- preload W' A-fragments: wave wv owns m-tiles {2wv, 2wv+1} (c in [32wv,32wv+32)) ----
  bf16x8 afr[2][6];
#pragma unroll
  for (int mtl = 0; mtl < 2; mtl++) {
    int c = (2 * wv + mtl) * 16 + col;
    const __hip_bfloat16* wrow = Wp + c * 192;
#pragma unroll
    for (int ks = 0; ks < 6; ks++)
      afr[mtl][ks] = *(const bf16x8*)(wrow + ks * 32 + kb);
  }

  // ---- init accumulators with bias2 (folds bias; garbage cols nn>=100 harmless) ----
  floatx4 acc[2][7];
#pragma unroll
  for (int nt = 0; nt < 7; nt++) {
    int nn = nt * 16 + col;
    int p = (nn * 41) >> 10;
    int w = nn - p * 25;
#pragma unroll
    for (int mtl = 0; mtl < 2; mtl++) {
      int c0 = (2 * wv + mtl) * 16 + quad * 4;
#pragma unroll
      for (int r = 0; r < 4; r++)
        acc[mtl][nt][r] = bias2[(c0 + r) * 25 + w];
    }
  }

  __syncthreads();

  // ---- stage B: out[c][(p,w)] = W' @ z  (M=128 over 4 waves x 2 tiles, N=112, K=192) ----
  const __hip_bfloat16* ztp = zt;
#pragma unroll
  for (int ks = 0; ks < 6; ks++) {
    bf16x8 bfr[7];
#pragma unroll
    for (int nt = 0; nt < 7; nt++)
      bfr[nt] = *(const bf16x8*)(ztp + (nt * 16 + col) * ROWK + ks * 32 + kb);
#pragma unroll
    for (int nt = 0; nt < 7; nt++) {
      acc[0][nt] = __builtin_amdgcn_mfma_f32_16x16x32_bf16(afr[0][ks], bfr[nt], acc[0][nt], 0, 0, 0);
      acc[1][nt] = __builtin_amdgcn_mfma_f32_16x16x32_bf16(afr[1][ks], bfr[nt], acc[1][nt], 0, 0, 0);
    }
  }

  // ---- epilogue: C/D layout col=lane&15 (nn), row=quad*4+reg (c) ----
#pragma unroll
  for (int nt = 0; nt < 7; nt++) {
    int nn = nt * 16 + col;
    if (nn >= 100) continue;
    int p = (nn * 41) >> 10;
    int w = nn - p * 25;
    int g = blk * 4 + p;
    int n = g >> 8, t = g & 255;
#pragma unroll
    for (int mtl = 0; mtl < 2; mtl++) {
      int c0 = (2 * wv + mtl) * 16 + quad * 4;
      size_t base = ((size_t)(n * 128 + c0) * 256 + t) * 25 + w;
#pragma unroll
      for (int r = 0; r < 4; r++)
        out[base + (size_t)r * 6400] = acc[mtl][nt][r];
    }
  }
}

extern "C" void kernel_launch(void* const* d_in, const int* in_sizes, int n_in,
                              void* d_out, int out_size, void* d_ws, size_t ws_size,
                              hipStream_t stream) {
  const float* x    = (const float*)d_in[0];
  const float* W    = (const float*)d_in[1];
  const float* b    = (const float*)d_in[2];
  const float* A    = (const float*)d_in[3];
  const float* edge = (const float*)d_in[4];
  const float* adA  = (const float*)d_in[5];
  float* out = (float*)d_out;

  char* ws = (char*)d_ws;
  __hip_bfloat16* Wp    = (__hip_bfloat16*)ws;           // 49152 B
  __hip_bfloat16* effAB = (__hip_bfloat16*)(ws + 49152); // 5120 B
  float* bias2          = (float*)(ws + 54272);          // 12800 B

  sgc_prep<<<64, 256, 0, stream>>>(W, b, A, edge, adA, Wp, effAB, bias2);
  sgc_main<<<4096, 256, 0, stream>>>(x, Wp, effAB, bias2, out);
}